// Round 4
// baseline (590.535 us; speedup 1.0000x reference)
//
#include <hip/hip_runtime.h>
#include <stdint.h>

#define BM 128
#define BN 128
#define BKK 64

typedef __attribute__((ext_vector_type(8))) __bf16 bf16x8;
typedef __attribute__((ext_vector_type(4))) float f32x4;

__device__ __forceinline__ unsigned short f2bf(float f) {
  unsigned u = __builtin_bit_cast(unsigned, f);
  u = (u + 0x7FFFu + ((u >> 16) & 1u)) >> 16;
  return (unsigned short)u;
}
__device__ __forceinline__ float bf2f(unsigned short h) {
  return __builtin_bit_cast(float, (unsigned)h << 16);
}

// global -> LDS direct copy, 16B per lane. LDS dest must be wave-uniform;
// HW adds lane*16 bytes.
__device__ __forceinline__ void gld_lds16(const void* g, void* l) {
  __builtin_amdgcn_global_load_lds(
      (const __attribute__((address_space(1))) void*)g,
      (__attribute__((address_space(3))) void*)l,
      16, 0, 0);
}

// ---------------- f32 -> bf16 conversion (vectorized x4) ----------------
__global__ void k_f32_to_bf16(const float* __restrict__ in,
                              unsigned short* __restrict__ out, int n4) {
  int i = blockIdx.x * blockDim.x + threadIdx.x;
  if (i >= n4) return;
  float4 v = ((const float4*)in)[i];
  ushort4 o;
  o.x = f2bf(v.x); o.y = f2bf(v.y); o.z = f2bf(v.z); o.w = f2bf(v.w);
  ((ushort4*)out)[i] = o;
}

// ---------------- GEMM: C[M,N](bf16) = A[M,K](bf16) * B[N,K](bf16)^T + bias ----
// 128x128 tile, BK=64, 4 waves (2x2). T3-minimum 2-phase double-buffer:
// stage tile t+1 into buf^1, compute tile t from buf, ONE __syncthreads per
// K-step (vmcnt(0)+lgkmcnt(0)+barrier, placed AFTER compute so the 8
// global_load_lds have the whole MFMA phase to land).
// STATS: per-column sum/sumsq via shfl-reduce + atomics in the epilogue.
template <bool STATS, bool RELU>
__global__ __launch_bounds__(256) void k_gemm_bt(
    const unsigned short* __restrict__ A, const unsigned short* __restrict__ B,
    const float* __restrict__ bias, unsigned short* __restrict__ C,
    float* __restrict__ sum, float* __restrict__ sumsq,
    int M, int N, int K) {
  __shared__ alignas(16) unsigned short As[2][BM * BKK];
  __shared__ alignas(16) unsigned short Bs[2][BN * BKK];

  // Bijective XCD-aware tile remap (m204): same-row tiles (sharing the A
  // panel) co-locate on one XCD's L2.
  const int gx = gridDim.x;
  const int nwg = gx * gridDim.y;
  const int flat = blockIdx.x + gx * blockIdx.y;
  const int q = nwg >> 3, r = nwg & 7;
  const int xcd = flat & 7, idx = flat >> 3;
  const int g = (xcd < r ? xcd * (q + 1) : r * (q + 1) + (xcd - r) * q) + idx;
  const int row0 = (g / gx) * BM;
  const int col0 = (g % gx) * BN;

  const int tid = threadIdx.x;
  const int lane = tid & 63;
  const int w = tid >> 6;
  const int wr = w >> 1, wc = w & 1;
  const int l15 = lane & 15, l4 = lane >> 4;

  f32x4 acc[4][4];
#pragma unroll
  for (int i = 0; i < 4; ++i)
#pragma unroll
    for (int j = 0; j < 4; ++j) acc[i][j] = f32x4{0.f, 0.f, 0.f, 0.f};

  auto stage = [&](int buf, int k0) {
#pragma unroll
    for (int i = 0; i < 4; ++i) {
      const int e = i * 2048 + w * 512 + lane * 8;  // element idx in 128x64 tile
      const int rr = e >> 6;
      const int c = e & 63;
      int ar = row0 + rr;
      ar = ar < M ? ar : M - 1;  // clamp edge tile (outputs masked later)
      gld_lds16(A + (size_t)ar * K + k0 + c, &As[buf][i * 2048 + w * 512]);
      gld_lds16(B + (size_t)(col0 + rr) * K + k0 + c, &Bs[buf][i * 2048 + w * 512]);
    }
  };
  auto compute = [&](int buf) {
#pragma unroll
    for (int kk = 0; kk < 2; ++kk) {
      bf16x8 a[4], b[4];
#pragma unroll
      for (int mi = 0; mi < 4; ++mi)
        a[mi] = *(const bf16x8*)(&As[buf][(wr * 64 + mi * 16 + l15) * BKK + kk * 32 + l4 * 8]);
#pragma unroll
      for (int ni = 0; ni < 4; ++ni)
        b[ni] = *(const bf16x8*)(&Bs[buf][(wc * 64 + ni * 16 + l15) * BKK + kk * 32 + l4 * 8]);
#pragma unroll
      for (int mi = 0; mi < 4; ++mi)
#pragma unroll
        for (int ni = 0; ni < 4; ++ni)
          acc[mi][ni] = __builtin_amdgcn_mfma_f32_16x16x32_bf16(a[mi], b[ni], acc[mi][ni], 0, 0, 0);
    }
  };

  const int nt = K / BKK;
  stage(0, 0);
  __syncthreads();  // vmcnt(0) drain + barrier: buf0 ready
  int cur = 0;
  for (int t = 0; t < nt - 1; ++t) {
    stage(cur ^ 1, (t + 1) * BKK);  // prefetch next tile (in flight across compute)
    compute(cur);
    __syncthreads();  // after compute: loads had the whole phase to land
    cur ^= 1;
  }
  compute(cur);

  // epilogue: bias (+relu) -> bf16 store; optional per-column stats.
  // C/D layout: col = lane&15, row = (lane>>4)*4 + reg.
  float s[4] = {0.f, 0.f, 0.f, 0.f}, qs[4] = {0.f, 0.f, 0.f, 0.f};
#pragma unroll
  for (int mi = 0; mi < 4; ++mi) {
    const int rbase = row0 + wr * 64 + mi * 16 + l4 * 4;
#pragma unroll
    for (int ni = 0; ni < 4; ++ni) {
      const int col = col0 + wc * 64 + ni * 16 + l15;
      const float bv = bias[col];
#pragma unroll
      for (int rr = 0; rr < 4; ++rr) {
        const int row = rbase + rr;
        if (row < M) {
          float v = acc[mi][ni][rr] + bv;
          if (RELU) v = fmaxf(v, 0.f);
          C[(size_t)row * N + col] = f2bf(v);
          if (STATS) { s[ni] += v; qs[ni] += v * v; }
        }
      }
    }
  }
  if (STATS) {
#pragma unroll
    for (int ni = 0; ni < 4; ++ni) {
      s[ni] += __shfl_xor(s[ni], 16, 64);
      s[ni] += __shfl_xor(s[ni], 32, 64);
      qs[ni] += __shfl_xor(qs[ni], 16, 64);
      qs[ni] += __shfl_xor(qs[ni], 32, 64);
    }
    if (l4 == 0) {  // lanes 0..15 hold the full 64-row partials
#pragma unroll
      for (int ni = 0; ni < 4; ++ni) {
        const int col = col0 + wc * 64 + ni * 16 + l15;
        atomicAdd(&sum[col], s[ni]);
        atomicAdd(&sumsq[col], qs[ni]);
      }
    }
  }
}

__global__ void k_bn_finalize(const float* __restrict__ sum, const float* __restrict__ sumsq,
                              const float* __restrict__ g, const float* __restrict__ be,
                              float* __restrict__ scale, float* __restrict__ shift,
                              int M, int N) {
  int c = blockIdx.x * blockDim.x + threadIdx.x;
  if (c >= N) return;
  float inv = 1.f / (float)M;
  float mean = sum[c] * inv;
  float var = sumsq[c] * inv - mean * mean;  // biased (torch train semantics)
  float sc = g[c] * rsqrtf(var + 1e-5f);
  scale[c] = sc;
  shift[c] = be[c] - mean * sc;
}

// in-place: h <- relu(h*scale + shift), bf16, 8 elems/thread (16B)
__global__ void k_bn_apply(unsigned short* __restrict__ Hb,
                           const float* __restrict__ scale,
                           const float* __restrict__ shift, size_t total8) {
  size_t i = (size_t)blockIdx.x * blockDim.x + threadIdx.x;
  if (i >= total8) return;
  size_t b = i * 8;
  uint4 v = *(uint4*)(Hb + b);
  const int c = (int)(b & 1023);  // H == 1024
  const float4 sc0 = *(const float4*)(scale + c);
  const float4 sc1 = *(const float4*)(scale + c + 4);
  const float4 sh0 = *(const float4*)(shift + c);
  const float4 sh1 = *(const float4*)(shift + c + 4);
  auto nrm = [](unsigned u, float scl, float sfh) -> unsigned {
    return (unsigned)f2bf(fmaxf(fmaf(bf2f((unsigned short)u), scl, sfh), 0.f));
  };
  uint4 o;
  o.x = nrm(v.x & 0xFFFF, sc0.x, sh0.x) | (nrm(v.x >> 16, sc0.y, sh0.y) << 16);
  o.y = nrm(v.y & 0xFFFF, sc0.z, sh0.z) | (nrm(v.y >> 16, sc0.w, sh0.w) << 16);
  o.z = nrm(v.z & 0xFFFF, sc1.x, sh1.x) | (nrm(v.z >> 16, sc1.y, sh1.y) << 16);
  o.w = nrm(v.w & 0xFFFF, sc1.z, sh1.z) | (nrm(v.w >> 16, sc1.w, sh1.w) << 16);
  *(uint4*)(Hb + b) = o;
}

// ---------------- head: logits = H3[M,256](bf16) @ Wl2[10,256]^T + bl2; log_softmax ----
__global__ __launch_bounds__(256) void k_head(const unsigned short* __restrict__ H3,
                                              const float* __restrict__ W,  // [10,256] f32
                                              const float* __restrict__ bias,
                                              float* __restrict__ out, int M) {
  __shared__ float Ws[10 * 256];
  for (int i = threadIdx.x; i < 2560; i += 256) Ws[i] = W[i];
  __syncthreads();
  const int wv = threadIdx.x >> 6;
  const int lane = threadIdx.x & 63;
  const int row = blockIdx.x * 4 + wv;
  if (row >= M) return;
  const ushort4 hv = *(const ushort4*)(H3 + (size_t)row * 256 + lane * 4);
  const float h0 = bf2f(hv.x), h1 = bf2f(hv.y), h2 = bf2f(hv.z), h3 = bf2f(hv.w);
  float acc[10];
#pragma unroll
  for (int o = 0; o < 10; ++o) {
    const float* wp = Ws + o * 256 + lane * 4;
    acc[o] = h0 * wp[0] + h1 * wp[1] + h2 * wp[2] + h3 * wp[3];
  }
#pragma unroll
  for (int d = 1; d < 64; d <<= 1)
#pragma unroll
    for (int o = 0; o < 10; ++o) acc[o] += __shfl_xor(acc[o], d, 64);
  if (lane == 0) {
    float lg[10], mx = -1e30f;
#pragma unroll
    for (int o = 0; o < 10; ++o) {
      lg[o] = acc[o] + bias[o];
      mx = fmaxf(mx, lg[o]);
    }
    float ssum = 0.f;
#pragma unroll
    for (int o = 0; o < 10; ++o) ssum += expf(lg[o] - mx);
    float ls = logf(ssum);
#pragma unroll
    for (int o = 0; o < 10; ++o) out[(size_t)row * 10 + o] = lg[o] - mx - ls;
  }
}

extern "C" void kernel_launch(void* const* d_in, const int* in_sizes, int n_in,
                              void* d_out, int out_size, void* d_ws, size_t ws_size,
                              hipStream_t stream) {
  const float* x = (const float*)d_in[0];
  // d_in[1] = edge_index (int64), d_in[2] = edge_weight — unused (ChebConv K=1)
  const float* W1 = (const float*)d_in[3];
  const float* b1 = (const float*)d_in[4];
  const float* g1 = (const float*)d_in[5];
  const float* be1 = (const float*)d_in[6];
  const float* W2 = (const float*)d_in[7];
  const float* b2 = (const float*)d_in[8];
  const float* g2 = (const float*)d_in[9];
  const float* be2 = (const float*)d_in[10];
  const float* Wl1 = (const float*)d_in[11];
  const float* bl1 = (const float*)d_in[12];
  const float* Wl2 = (const float*)d_in[13];
  const float* bl2 = (const float*)d_in[14];

  const int Din = 128, H = 1024, Hm = 256;
  const int M = in_sizes[0] / Din;  // 50000

  char* ws = (char*)d_ws;
  size_t off = 0;
  auto alloc = [&](size_t b) -> void* {
    void* p = ws + off;
    off += (b + 255) & ~(size_t)255;
    return p;
  };

  // total ws use ~= 207.6 MB
  float* sum1 = (float*)alloc(H * 4);
  float* sumsq1 = (float*)alloc(H * 4);
  float* sum2 = (float*)alloc(H * 4);
  float* sumsq2 = (float*)alloc(H * 4);
  float* scale1 = (float*)alloc(H * 4);
  float* shift1 = (float*)alloc(H * 4);
  float* scale2 = (float*)alloc(H * 4);
  float* shift2 = (float*)alloc(H * 4);
  unsigned short* W1b = (unsigned short*)alloc((size_t)H * Din * 2);
  unsigned short* W2b = (unsigned short*)alloc((size_t)H * H * 2);
  unsigned short* Wl1b = (unsigned short*)alloc((size_t)Hm * H * 2);
  unsigned short* h1 = (unsigned short*)alloc((size_t)M * H * 2);   // raw->norm h1; later h3
  unsigned short* h2 = (unsigned short*)alloc((size_t)M * H * 2);   // xb first, then h2
  unsigned short* xb = h2;            // x(bf16) [M,128] — dead once GEMM2 writes h2
  unsigned short* h3 = h1;            // h3 [M,256] bf16 — h1 dead after GEMM2

  // zero the 4 stat accumulators (contiguous 16 KB; ws is poisoned 0xAA)
  hipMemsetAsync(sum1, 0, (size_t)H * 4 * 4, stream);

  // f32 -> bf16 conversions
  int n4;
  n4 = M * Din / 4;
  k_f32_to_bf16<<<(n4 + 255) / 256, 256, 0, stream>>>(x, xb, n4);
  n4 = H * Din / 4;
  k_f32_to_bf16<<<(n4 + 255) / 256, 256, 0, stream>>>(W1, W1b, n4);
  n4 = H * H / 4;
  k_f32_to_bf16<<<(n4 + 255) / 256, 256, 0, stream>>>(W2, W2b, n4);
  n4 = Hm * H / 4;
  k_f32_to_bf16<<<(n4 + 255) / 256, 256, 0, stream>>>(Wl1, Wl1b, n4);

  const int MT = (M + BM - 1) / BM;  // 391
  dim3 blk(256);
  const size_t total8 = (size_t)M * H / 8;
  const int apblk = (int)((total8 + 255) / 256);

  // layer 1: h1 = x @ W1^T + b1 (bf16 out, stats fused)
  k_gemm_bt<true, false><<<dim3(H / BN, MT), blk, 0, stream>>>(
      xb, W1b, b1, h1, sum1, sumsq1, M, H, Din);
  k_bn_finalize<<<H / 256, 256, 0, stream>>>(sum1, sumsq1, g1, be1, scale1, shift1, M, H);
  k_bn_apply<<<apblk, 256, 0, stream>>>(h1, scale1, shift1, total8);

  // layer 2: h2 = h1' @ W2^T + b2
  k_gemm_bt<true, false><<<dim3(H / BN, MT), blk, 0, stream>>>(
      h1, W2b, b2, h2, sum2, sumsq2, M, H, H);
  k_bn_finalize<<<H / 256, 256, 0, stream>>>(sum2, sumsq2, g2, be2, scale2, shift2, M, H);
  k_bn_apply<<<apblk, 256, 0, stream>>>(h2, scale2, shift2, total8);

  // layer 3: h3 = relu(h2' @ Wl1^T + bl1), bf16 out (no stats)
  k_gemm_bt<false, true><<<dim3(Hm / BN, MT), blk, 0, stream>>>(
      h2, Wl1b, bl1, h3, nullptr, nullptr, M, Hm, H);

  // head: logits + log_softmax (f32 out)
  k_head<<<(M + 3) / 4, 256, 0, stream>>>(h3, Wl2, bl2, (float*)d_out, M);
}

// Round 5
// 502.780 us; speedup vs baseline: 1.1745x; 1.1745x over previous
//
#include <hip/hip_runtime.h>
#include <stdint.h>

#define BM 256
#define BN 128
#define BKK 64

typedef __attribute__((ext_vector_type(8))) __bf16 bf16x8;
typedef __attribute__((ext_vector_type(4))) float f32x4;

__device__ __forceinline__ unsigned short f2bf(float f) {
  unsigned u = __builtin_bit_cast(unsigned, f);
  u = (u + 0x7FFFu + ((u >> 16) & 1u)) >> 16;
  return (unsigned short)u;
}
__device__ __forceinline__ float bf2f(unsigned short h) {
  return __builtin_bit_cast(float, (unsigned)h << 16);
}

// global -> LDS direct copy, 16B per lane. LDS dest must be wave-uniform;
// HW adds lane*16 bytes.
__device__ __forceinline__ void gld_lds16(const void* g, void* l) {
  __builtin_amdgcn_global_load_lds(
      (const __attribute__((address_space(1))) void*)g,
      (__attribute__((address_space(3))) void*)l,
      16, 0, 0);
}

// ---------------- f32 -> bf16 conversion (vectorized x4) ----------------
__global__ void k_f32_to_bf16(const float* __restrict__ in,
                              unsigned short* __restrict__ out, int n4) {
  int i = blockIdx.x * blockDim.x + threadIdx.x;
  if (i >= n4) return;
  float4 v = ((const float4*)in)[i];
  ushort4 o;
  o.x = f2bf(v.x); o.y = f2bf(v.y); o.z = f2bf(v.z); o.w = f2bf(v.w);
  ((ushort4*)out)[i] = o;
}

// ---------------- GEMM: C[M,N](bf16) = A[M,K](bf16) * B[N,K](bf16)^T + bias ----
// 256x128 tile, BK=64, single-buffer 2-barrier loop (round-2 proven structure).
// 4 waves (2x2): per-wave subtile 128x64 = 8x4 MFMA frags -> 64 MFMA/wave/K-step
// (2x the work per exposed stage+drain stall vs 128x128).
// STATS: per-column sum/sumsq via shfl-reduce + atomics in the epilogue.
template <bool STATS, bool RELU>
__global__ __launch_bounds__(256, 2) void k_gemm_bt(
    const unsigned short* __restrict__ A, const unsigned short* __restrict__ B,
    const float* __restrict__ bias, unsigned short* __restrict__ C,
    float* __restrict__ sum, float* __restrict__ sumsq,
    int M, int N, int K) {
  __shared__ alignas(16) unsigned short As[BM * BKK];  // 32 KB
  __shared__ alignas(16) unsigned short Bs[BN * BKK];  // 16 KB

  // Bijective XCD-aware tile remap (m204): same-row tiles (sharing the A
  // panel) co-locate on one XCD's L2.
  const int gx = gridDim.x;
  const int nwg = gx * gridDim.y;
  const int flat = blockIdx.x + gx * blockIdx.y;
  const int q = nwg >> 3, r = nwg & 7;
  const int xcd = flat & 7, idx = flat >> 3;
  const int g = (xcd < r ? xcd * (q + 1) : r * (q + 1) + (xcd - r) * q) + idx;
  const int row0 = (g / gx) * BM;
  const int col0 = (g % gx) * BN;

  const int tid = threadIdx.x;
  const int lane = tid & 63;
  const int w = tid >> 6;
  const int wr = w >> 1, wc = w & 1;   // wave row-half (0..1), col-half (0..1)
  const int l15 = lane & 15, l4 = lane >> 4;

  f32x4 acc[8][4];
#pragma unroll
  for (int i = 0; i < 8; ++i)
#pragma unroll
    for (int j = 0; j < 4; ++j) acc[i][j] = f32x4{0.f, 0.f, 0.f, 0.f};

  for (int k0 = 0; k0 < K; k0 += BKK) {
    // stage A (256x64) : 8 gld_lds/thread, B (128x64) : 4 gld_lds/thread
#pragma unroll
    for (int i = 0; i < 8; ++i) {
      const int e = i * 2048 + w * 512 + lane * 8;  // element idx in 256x64 tile
      const int rr = e >> 6;
      const int c = e & 63;
      int ar = row0 + rr;
      ar = ar < M ? ar : M - 1;  // clamp edge tile (outputs masked later)
      gld_lds16(A + (size_t)ar * K + k0 + c, As + i * 2048 + w * 512);
    }
#pragma unroll
    for (int i = 0; i < 4; ++i) {
      const int e = i * 2048 + w * 512 + lane * 8;  // element idx in 128x64 tile
      const int rr = e >> 6;
      const int c = e & 63;
      gld_lds16(B + (size_t)(col0 + rr) * K + k0 + c, Bs + i * 2048 + w * 512);
    }
    __syncthreads();  // vmcnt(0) drain: tile visible
#pragma unroll
    for (int kk = 0; kk < 2; ++kk) {
      bf16x8 a[8], b[4];
#pragma unroll
      for (int mi = 0; mi < 8; ++mi)
        a[mi] = *(const bf16x8*)(As + (wr * 128 + mi * 16 + l15) * BKK + kk * 32 + l4 * 8);
#pragma unroll
      for (int ni = 0; ni < 4; ++ni)
        b[ni] = *(const bf16x8*)(Bs + (wc * 64 + ni * 16 + l15) * BKK + kk * 32 + l4 * 8);
#pragma unroll
      for (int mi = 0; mi < 8; ++mi)
#pragma unroll
        for (int ni = 0; ni < 4; ++ni)
          acc[mi][ni] = __builtin_amdgcn_mfma_f32_16x16x32_bf16(a[mi], b[ni], acc[mi][ni], 0, 0, 0);
    }
    __syncthreads();  // protect LDS overwrite next step
  }

  // epilogue: bias (+relu) -> bf16 store; optional per-column stats.
  // C/D layout: col = lane&15, row = (lane>>4)*4 + reg.
  float s[4] = {0.f, 0.f, 0.f, 0.f}, qs[4] = {0.f, 0.f, 0.f, 0.f};
#pragma unroll
  for (int mi = 0; mi < 8; ++mi) {
    const int rbase = row0 + wr * 128 + mi * 16 + l4 * 4;
#pragma unroll
    for (int ni = 0; ni < 4; ++ni) {
      const int col = col0 + wc * 64 + ni * 16 + l15;
      const float bv = bias[col];
#pragma unroll
      for (int rr = 0; rr < 4; ++rr) {
        const int row = rbase + rr;
        if (row < M) {
          float v = acc[mi][ni][rr] + bv;
          if (RELU) v = fmaxf(v, 0.f);
          C[(size_t)row * N + col] = f2bf(v);
          if (STATS) { s[ni] += v; qs[ni] += v * v; }
        }
      }
    }
  }
  if (STATS) {
#pragma unroll
    for (int ni = 0; ni < 4; ++ni) {
      s[ni] += __shfl_xor(s[ni], 16, 64);
      s[ni] += __shfl_xor(s[ni], 32, 64);
      qs[ni] += __shfl_xor(qs[ni], 16, 64);
      qs[ni] += __shfl_xor(qs[ni], 32, 64);
    }
    if (l4 == 0) {  // lanes 0..15 hold the full 128-row partials
#pragma unroll
      for (int ni = 0; ni < 4; ++ni) {
        const int col = col0 + wc * 64 + ni * 16 + l15;
        atomicAdd(&sum[col], s[ni]);
        atomicAdd(&sumsq[col], qs[ni]);
      }
    }
  }
}

__global__ void k_bn_finalize(const float* __restrict__ sum, const float* __restrict__ sumsq,
                              const float* __restrict__ g, const float* __restrict__ be,
                              float* __restrict__ scale, float* __restrict__ shift,
                              int M, int N) {
  int c = blockIdx.x * blockDim.x + threadIdx.x;
  if (c >= N) return;
  float inv = 1.f / (float)M;
  float mean = sum[c] * inv;
  float var = sumsq[c] * inv - mean * mean;  // biased (torch train semantics)
  float sc = g[c] * rsqrtf(var + 1e-5f);
  scale[c] = sc;
  shift[c] = be[c] - mean * sc;
}

// in-place: h <- relu(h*scale + shift), bf16, 8 elems/thread (16B)
__global__ void k_bn_apply(unsigned short* __restrict__ Hb,
                           const float* __restrict__ scale,
                           const float* __restrict__ shift, size_t total8) {
  size_t i = (size_t)blockIdx.x * blockDim.x + threadIdx.x;
  if (i >= total8) return;
  size_t b = i * 8;
  uint4 v = *(uint4*)(Hb + b);
  const int c = (int)(b & 1023);  // H == 1024
  const float4 sc0 = *(const float4*)(scale + c);
  const float4 sc1 = *(const float4*)(scale + c + 4);
  const float4 sh0 = *(const float4*)(shift + c);
  const float4 sh1 = *(const float4*)(shift + c + 4);
  auto nrm = [](unsigned u, float scl, float sfh) -> unsigned {
    return (unsigned)f2bf(fmaxf(fmaf(bf2f((unsigned short)u), scl, sfh), 0.f));
  };
  uint4 o;
  o.x = nrm(v.x & 0xFFFF, sc0.x, sh0.x) | (nrm(v.x >> 16, sc0.y, sh0.y) << 16);
  o.y = nrm(v.y & 0xFFFF, sc0.z, sh0.z) | (nrm(v.y >> 16, sc0.w, sh0.w) << 16);
  o.z = nrm(v.z & 0xFFFF, sc1.x, sh1.x) | (nrm(v.z >> 16, sc1.y, sh1.y) << 16);
  o.w = nrm(v.w & 0xFFFF, sc1.z, sh1.z) | (nrm(v.w >> 16, sc1.w, sh1.w) << 16);
  *(uint4*)(Hb + b) = o;
}

// ---------------- head: logits = H3[M,256](bf16) @ Wl2[10,256]^T + bl2; log_softmax ----
__global__ __launch_bounds__(256) void k_head(const unsigned short* __restrict__ H3,
                                              const float* __restrict__ W,  // [10,256] f32
                                              const float* __restrict__ bias,
                                              float* __restrict__ out, int M) {
  __shared__ float Ws[10 * 256];
  for (int i = threadIdx.x; i < 2560; i += 256) Ws[i] = W[i];
  __syncthreads();
  const int wv = threadIdx.x >> 6;
  const int lane = threadIdx.x & 63;
  const int row = blockIdx.x * 4 + wv;
  if (row >= M) return;
  const ushort4 hv = *(const ushort4*)(H3 + (size_t)row * 256 + lane * 4);
  const float h0 = bf2f(hv.x), h1 = bf2f(hv.y), h2 = bf2f(hv.z), h3 = bf2f(hv.w);
  float acc[10];
#pragma unroll
  for (int o = 0; o < 10; ++o) {
    const float* wp = Ws + o * 256 + lane * 4;
    acc[o] = h0 * wp[0] + h1 * wp[1] + h2 * wp[2] + h3 * wp[3];
  }
#pragma unroll
  for (int d = 1; d < 64; d <<= 1)
#pragma unroll
    for (int o = 0; o < 10; ++o) acc[o] += __shfl_xor(acc[o], d, 64);
  if (lane == 0) {
    float lg[10], mx = -1e30f;
#pragma unroll
    for (int o = 0; o < 10; ++o) {
      lg[o] = acc[o] + bias[o];
      mx = fmaxf(mx, lg[o]);
    }
    float ssum = 0.f;
#pragma unroll
    for (int o = 0; o < 10; ++o) ssum += expf(lg[o] - mx);
    float ls = logf(ssum);
#pragma unroll
    for (int o = 0; o < 10; ++o) out[(size_t)row * 10 + o] = lg[o] - mx - ls;
  }
}

extern "C" void kernel_launch(void* const* d_in, const int* in_sizes, int n_in,
                              void* d_out, int out_size, void* d_ws, size_t ws_size,
                              hipStream_t stream) {
  const float* x = (const float*)d_in[0];
  // d_in[1] = edge_index (int64), d_in[2] = edge_weight — unused (ChebConv K=1)
  const float* W1 = (const float*)d_in[3];
  const float* b1 = (const float*)d_in[4];
  const float* g1 = (const float*)d_in[5];
  const float* be1 = (const float*)d_in[6];
  const float* W2 = (const float*)d_in[7];
  const float* b2 = (const float*)d_in[8];
  const float* g2 = (const float*)d_in[9];
  const float* be2 = (const float*)d_in[10];
  const float* Wl1 = (const float*)d_in[11];
  const float* bl1 = (const float*)d_in[12];
  const float* Wl2 = (const float*)d_in[13];
  const float* bl2 = (const float*)d_in[14];

  const int Din = 128, H = 1024, Hm = 256;
  const int M = in_sizes[0] / Din;  // 50000

  char* ws = (char*)d_ws;
  size_t off = 0;
  auto alloc = [&](size_t b) -> void* {
    void* p = ws + off;
    off += (b + 255) & ~(size_t)255;
    return p;
  };

  // total ws use ~= 207.6 MB
  float* sum1 = (float*)alloc(H * 4);
  float* sumsq1 = (float*)alloc(H * 4);
  float* sum2 = (float*)alloc(H * 4);
  float* sumsq2 = (float*)alloc(H * 4);
  float* scale1 = (float*)alloc(H * 4);
  float* shift1 = (float*)alloc(H * 4);
  float* scale2 = (float*)alloc(H * 4);
  float* shift2 = (float*)alloc(H * 4);
  unsigned short* W1b = (unsigned short*)alloc((size_t)H * Din * 2);
  unsigned short* W2b = (unsigned short*)alloc((size_t)H * H * 2);
  unsigned short* Wl1b = (unsigned short*)alloc((size_t)Hm * H * 2);
  unsigned short* h1 = (unsigned short*)alloc((size_t)M * H * 2);   // raw->norm h1; later h3
  unsigned short* h2 = (unsigned short*)alloc((size_t)M * H * 2);   // xb first, then h2
  unsigned short* xb = h2;            // x(bf16) [M,128] — dead once GEMM2 writes h2
  unsigned short* h3 = h1;            // h3 [M,256] bf16 — h1 dead after GEMM2

  // zero the 4 stat accumulators (contiguous 16 KB; ws is poisoned 0xAA)
  hipMemsetAsync(sum1, 0, (size_t)H * 4 * 4, stream);

  // f32 -> bf16 conversions
  int n4;
  n4 = M * Din / 4;
  k_f32_to_bf16<<<(n4 + 255) / 256, 256, 0, stream>>>(x, xb, n4);
  n4 = H * Din / 4;
  k_f32_to_bf16<<<(n4 + 255) / 256, 256, 0, stream>>>(W1, W1b, n4);
  n4 = H * H / 4;
  k_f32_to_bf16<<<(n4 + 255) / 256, 256, 0, stream>>>(W2, W2b, n4);
  n4 = Hm * H / 4;
  k_f32_to_bf16<<<(n4 + 255) / 256, 256, 0, stream>>>(Wl1, Wl1b, n4);

  const int MT = (M + BM - 1) / BM;  // 196
  dim3 blk(256);
  const size_t total8 = (size_t)M * H / 8;
  const int apblk = (int)((total8 + 255) / 256);

  // layer 1: h1 = x @ W1^T + b1 (bf16 out, stats fused)
  k_gemm_bt<true, false><<<dim3(H / BN, MT), blk, 0, stream>>>(
      xb, W1b, b1, h1, sum1, sumsq1, M, H, Din);
  k_bn_finalize<<<H / 256, 256, 0, stream>>>(sum1, sumsq1, g1, be1, scale1, shift1, M, H);
  k_bn_apply<<<apblk, 256, 0, stream>>>(h1, scale1, shift1, total8);

  // layer 2: h2 = h1' @ W2^T + b2
  k_gemm_bt<true, false><<<dim3(H / BN, MT), blk, 0, stream>>>(
      h1, W2b, b2, h2, sum2, sumsq2, M, H, H);
  k_bn_finalize<<<H / 256, 256, 0, stream>>>(sum2, sumsq2, g2, be2, scale2, shift2, M, H);
  k_bn_apply<<<apblk, 256, 0, stream>>>(h2, scale2, shift2, total8);

  // layer 3: h3 = relu(h2' @ Wl1^T + bl1), bf16 out (no stats)
  k_gemm_bt<false, true><<<dim3(Hm / BN, MT), blk, 0, stream>>>(
      h2, Wl1b, bl1, h3, nullptr, nullptr, M, Hm, H);

  // head: logits + log_softmax (f32 out)
  k_head<<<(M + 3) / 4, 256, 0, stream>>>(h3, Wl2, bl2, (float*)d_out, M);
}

// Round 7
// 485.340 us; speedup vs baseline: 1.2167x; 1.0359x over previous
//
#include <hip/hip_runtime.h>
#include <stdint.h>

#define BM 256
#define BN 128
#define BKK 64

typedef __attribute__((ext_vector_type(8))) __bf16 bf16x8;
typedef __attribute__((ext_vector_type(4))) float f32x4;

__device__ __forceinline__ unsigned short f2bf(float f) {
  unsigned u = __builtin_bit_cast(unsigned, f);
  u = (u + 0x7FFFu + ((u >> 16) & 1u)) >> 16;
  return (unsigned short)u;
}
__device__ __forceinline__ float bf2f(unsigned short h) {
  return __builtin_bit_cast(float, (unsigned)h << 16);
}

// global -> LDS direct copy, 16B per lane. LDS dest must be wave-uniform;
// HW adds lane*16 bytes.
__device__ __forceinline__ void gld_lds16(const void* g, void* l) {
  __builtin_amdgcn_global_load_lds(
      (const __attribute__((address_space(1))) void*)g,
      (__attribute__((address_space(3))) void*)l,
      16, 0, 0);
}

// ---------------- f32 -> bf16 conversion (vectorized x4) ----------------
__global__ void k_f32_to_bf16(const float* __restrict__ in,
                              unsigned short* __restrict__ out, int n4) {
  int i = blockIdx.x * blockDim.x + threadIdx.x;
  if (i >= n4) return;
  float4 v = ((const float4*)in)[i];
  ushort4 o;
  o.x = f2bf(v.x); o.y = f2bf(v.y); o.z = f2bf(v.z); o.w = f2bf(v.w);
  ((ushort4*)out)[i] = o;
}

// ---------------- GEMM: C[M,N](bf16) = A[M,K](bf16) * B[N,K](bf16)^T + bias ----
// 256x128 tile, BK=64, single-buffer 2-barrier loop. 4 waves (2x2), per-wave
// 128x64 = 8x4 MFMA frags.
// T2 both-sides XOR swizzle (rule #21): LDS rows are 128B so naive frag reads
// are 16-way bank conflicts (lanes 0-15 at stride 128B -> same bank column;
// measured 2.89e7 conflict cycles = 26% of dur). gld_lds writes linearly, so
// we pre-swizzle the GLOBAL source column (c4 ^= row&7, == ((lane&7)^(lane>>3))
// wave-uniform) and apply the same XOR on the ds_read address. Involution:
// reader recovers exactly G[row][c4*8+j]; lanes spread over 8 distinct 16B
// slots (2-way aliasing = free).
// STATS: per-column sum/sumsq via shfl-reduce + atomics in the epilogue.
template <bool STATS, bool RELU>
__global__ __launch_bounds__(256, 2) void k_gemm_bt(
    const unsigned short* __restrict__ A, const unsigned short* __restrict__ B,
    const float* __restrict__ bias, unsigned short* __restrict__ C,
    float* __restrict__ sum, float* __restrict__ sumsq,
    int M, int N, int K) {
  __shared__ alignas(16) unsigned short As[BM * BKK];  // 32 KB
  __shared__ alignas(16) unsigned short Bs[BN * BKK];  // 16 KB

  // Bijective XCD-aware tile remap (m204): same-row tiles (sharing the A
  // panel) co-locate on one XCD's L2.
  const int gx = gridDim.x;
  const int nwg = gx * gridDim.y;
  const int flat = blockIdx.x + gx * blockIdx.y;
  const int q = nwg >> 3, r = nwg & 7;
  const int xcd = flat & 7, idx = flat >> 3;
  const int g = (xcd < r ? xcd * (q + 1) : r * (q + 1) + (xcd - r) * q) + idx;
  const int row0 = (g / gx) * BM;
  const int col0 = (g % gx) * BN;

  const int tid = threadIdx.x;
  const int lane = tid & 63;
  const int w = tid >> 6;
  const int wr = w >> 1, wc = w & 1;   // wave row-half (0..1), col-half (0..1)
  const int l15 = lane & 15, l4 = lane >> 4;

  // swizzled source column for staging: row&7 == lane>>3 for every staging
  // instr (i*32 + w*8 row offsets are 0 mod 8), col4 == lane&7.
  const int c_swz = (((lane & 7) ^ (lane >> 3)) * 8);

  f32x4 acc[8][4];
#pragma unroll
  for (int i = 0; i < 8; ++i)
#pragma unroll
    for (int j = 0; j < 4; ++j) acc[i][j] = f32x4{0.f, 0.f, 0.f, 0.f};

  for (int k0 = 0; k0 < K; k0 += BKK) {
    // stage A (256x64): 8 gld_lds/thread, B (128x64): 4 gld_lds/thread
#pragma unroll
    for (int i = 0; i < 8; ++i) {
      const int e = i * 2048 + w * 512 + lane * 8;  // linear elem idx in tile
      const int rr = e >> 6;
      int ar = row0 + rr;
      ar = ar < M ? ar : M - 1;  // clamp edge tile (outputs masked later)
      gld_lds16(A + (size_t)ar * K + k0 + c_swz, As + i * 2048 + w * 512);
    }
#pragma unroll
    for (int i = 0; i < 4; ++i) {
      const int e = i * 2048 + w * 512 + lane * 8;
      const int rr = e >> 6;
      gld_lds16(B + (size_t)(col0 + rr) * K + k0 + c_swz, Bs + i * 2048 + w * 512);
    }
    __syncthreads();  // vmcnt(0) drain: tile visible
#pragma unroll
    for (int kk = 0; kk < 2; ++kk) {
      // swizzled read column: c4 = kk*4 + l4, XOR row&7 (= l15&7)
      const int cs = (((kk * 4 + l4) ^ (l15 & 7)) * 8);
      bf16x8 a[8], b[4];
#pragma unroll
      for (int mi = 0; mi < 8; ++mi)
        a[mi] = *(const bf16x8*)(As + (wr * 128 + mi * 16 + l15) * BKK + cs);
#pragma unroll
      for (int ni = 0; ni < 4; ++ni)
        b[ni] = *(const bf16x8*)(Bs + (wc * 64 + ni * 16 + l15) * BKK + cs);
#pragma unroll
      for (int mi = 0; mi < 8; ++mi)
#pragma unroll
        for (int ni = 0; ni < 4; ++ni)
          acc[mi][ni] = __builtin_amdgcn_mfma_f32_16x16x32_bf16(a[mi], b[ni], acc[mi][ni], 0, 0, 0);
    }
    __syncthreads();  // protect LDS overwrite next step
  }

  // epilogue: bias (+relu) -> bf16 store; optional per-column stats.
  // C/D layout: col = lane&15, row = (lane>>4)*4 + reg.
  float s[4] = {0.f, 0.f, 0.f, 0.f}, qs[4] = {0.f, 0.f, 0.f, 0.f};
#pragma unroll
  for (int mi = 0; mi < 8; ++mi) {
    const int rbase = row0 + wr * 128 + mi * 16 + l4 * 4;
#pragma unroll
    for (int ni = 0; ni < 4; ++ni) {
      const int col = col0 + wc * 64 + ni * 16 + l15;
      const float bv = bias[col];
#pragma unroll
      for (int rr = 0; rr < 4; ++rr) {
        const int row = rbase + rr;
        if (row < M) {
          float v = acc[mi][ni][rr] + bv;
          if (RELU) v = fmaxf(v, 0.f);
          C[(size_t)row * N + col] = f2bf(v);
          if (STATS) { s[ni] += v; qs[ni] += v * v; }
        }
      }
    }
  }
  if (STATS) {
#pragma unroll
    for (int ni = 0; ni < 4; ++ni) {
      s[ni] += __shfl_xor(s[ni], 16, 64);
      s[ni] += __shfl_xor(s[ni], 32, 64);
      qs[ni] += __shfl_xor(qs[ni], 16, 64);
      qs[ni] += __shfl_xor(qs[ni], 32, 64);
    }
    if (l4 == 0) {  // lanes 0..15 hold the full 128-row partials
#pragma unroll
      for (int ni = 0; ni < 4; ++ni) {
        const int col = col0 + wc * 64 + ni * 16 + l15;
        atomicAdd(&sum[col], s[ni]);
        atomicAdd(&sumsq[col], qs[ni]);
      }
    }
  }
}

__global__ void k_bn_finalize(const float* __restrict__ sum, const float* __restrict__ sumsq,
                              const float* __restrict__ g, const float* __restrict__ be,
                              float* __restrict__ scale, float* __restrict__ shift,
                              int M, int N) {
  int c = blockIdx.x * blockDim.x + threadIdx.x;
  if (c >= N) return;
  float inv = 1.f / (float)M;
  float mean = sum[c] * inv;
  float var = sumsq[c] * inv - mean * mean;  // biased (torch train semantics)
  float sc = g[c] * rsqrtf(var + 1e-5f);
  scale[c] = sc;
  shift[c] = be[c] - mean * sc;
}

// in-place: h <- relu(h*scale + shift), bf16, 8 elems/thread (16B)
__global__ void k_bn_apply(unsigned short* __restrict__ Hb,
                           const float* __restrict__ scale,
                           const float* __restrict__ shift, size_t total8) {
  size_t i = (size_t)blockIdx.x * blockDim.x + threadIdx.x;
  if (i >= total8) return;
  size_t b = i * 8;
  uint4 v = *(uint4*)(Hb + b);
  const int c = (int)(b & 1023);  // H == 1024
  const float4 sc0 = *(const float4*)(scale + c);
  const float4 sc1 = *(const float4*)(scale + c + 4);
  const float4 sh0 = *(const float4*)(shift + c);
  const float4 sh1 = *(const float4*)(shift + c + 4);
  auto nrm = [](unsigned u, float scl, float sfh) -> unsigned {
    return (unsigned)f2bf(fmaxf(fmaf(bf2f((unsigned short)u), scl, sfh), 0.f));
  };
  uint4 o;
  o.x = nrm(v.x & 0xFFFF, sc0.x, sh0.x) | (nrm(v.x >> 16, sc0.y, sh0.y) << 16);
  o.y = nrm(v.y & 0xFFFF, sc0.z, sh0.z) | (nrm(v.y >> 16, sc0.w, sh0.w) << 16);
  o.z = nrm(v.z & 0xFFFF, sc1.x, sh1.x) | (nrm(v.z >> 16, sc1.y, sh1.y) << 16);
  o.w = nrm(v.w & 0xFFFF, sc1.z, sh1.z) | (nrm(v.w >> 16, sc1.w, sh1.w) << 16);
  *(uint4*)(Hb + b) = o;
}

// ---------------- head: logits = H3[M,256](bf16) @ Wl2[10,256]^T + bl2; log_softmax ----
__global__ __launch_bounds__(256) void k_head(const unsigned short* __restrict__ H3,
                                              const float* __restrict__ W,  // [10,256] f32
                                              const float* __restrict__ bias,
                                              float* __restrict__ out, int M) {
  __shared__ float Ws[10 * 256];
  for (int i = threadIdx.x; i < 2560; i += 256) Ws[i] = W[i];
  __syncthreads();
  const int wv = threadIdx.x >> 6;
  const int lane = threadIdx.x & 63;
  const int row = blockIdx.x * 4 + wv;
  if (row >= M) return;
  const ushort4 hv = *(const ushort4*)(H3 + (size_t)row * 256 + lane * 4);
  const float h0 = bf2f(hv.x), h1 = bf2f(hv.y), h2 = bf2f(hv.z), h3 = bf2f(hv.w);
  float acc[10];
#pragma unroll
  for (int o = 0; o < 10; ++o) {
    const float* wp = Ws + o * 256 + lane * 4;
    acc[o] = h0 * wp[0] + h1 * wp[1] + h2 * wp[2] + h3 * wp[3];
  }
#pragma unroll
  for (int d = 1; d < 64; d <<= 1)
#pragma unroll
    for (int o = 0; o < 10; ++o) acc[o] += __shfl_xor(acc[o], d, 64);
  if (lane == 0) {
    float lg[10], mx = -1e30f;
#pragma unroll
    for (int o = 0; o < 10; ++o) {
      lg[o] = acc[o] + bias[o];
      mx = fmaxf(mx, lg[o]);
    }
    float ssum = 0.f;
#pragma unroll
    for (int o = 0; o < 10; ++o) ssum += expf(lg[o] - mx);
    float ls = logf(ssum);
#pragma unroll
    for (int o = 0; o < 10; ++o) out[(size_t)row * 10 + o] = lg[o] - mx - ls;
  }
}

extern "C" void kernel_launch(void* const* d_in, const int* in_sizes, int n_in,
                              void* d_out, int out_size, void* d_ws, size_t ws_size,
                              hipStream_t stream) {
  const float* x = (const float*)d_in[0];
  // d_in[1] = edge_index (int64), d_in[2] = edge_weight — unused (ChebConv K=1)
  const float* W1 = (const float*)d_in[3];
  const float* b1 = (const float*)d_in[4];
  const float* g1 = (const float*)d_in[5];
  const float* be1 = (const float*)d_in[6];
  const float* W2 = (const float*)d_in[7];
  const float* b2 = (const float*)d_in[8];
  const float* g2 = (const float*)d_in[9];
  const float* be2 = (const float*)d_in[10];
  const float* Wl1 = (const float*)d_in[11];
  const float* bl1 = (const float*)d_in[12];
  const float* Wl2 = (const float*)d_in[13];
  const float* bl2 = (const float*)d_in[14];

  const int Din = 128, H = 1024, Hm = 256;
  const int M = in_sizes[0] / Din;  // 50000

  char* ws = (char*)d_ws;
  size_t off = 0;
  auto alloc = [&](size_t b) -> void* {
    void* p = ws + off;
    off += (b + 255) & ~(size_t)255;
    return p;
  };

  // total ws use ~= 207.6 MB
  float* sum1 = (float*)alloc(H * 4);
  float* sumsq1 = (float*)alloc(H * 4);
  float* sum2 = (float*)alloc(H * 4);
  float* sumsq2 = (float*)alloc(H * 4);
  float* scale1 = (float*)alloc(H * 4);
  float* shift1 = (float*)alloc(H * 4);
  float* scale2 = (float*)alloc(H * 4);
  float* shift2 = (float*)alloc(H * 4);
  unsigned short* W1b = (unsigned short*)alloc((size_t)H * Din * 2);
  unsigned short* W2b = (unsigned short*)alloc((size_t)H * H * 2);
  unsigned short* Wl1b = (unsigned short*)alloc((size_t)Hm * H * 2);
  unsigned short* h1 = (unsigned short*)alloc((size_t)M * H * 2);   // raw->norm h1; later h3
  unsigned short* h2 = (unsigned short*)alloc((size_t)M * H * 2);   // xb first, then h2
  unsigned short* xb = h2;            // x(bf16) [M,128] — dead once GEMM2 writes h2
  unsigned short* h3 = h1;            // h3 [M,256] bf16 — h1 dead after GEMM2

  // zero the 4 stat accumulators (contiguous 16 KB; ws is poisoned 0xAA)
  hipMemsetAsync(sum1, 0, (size_t)H * 4 * 4, stream);

  // f32 -> bf16 conversions
  int n4;
  n4 = M * Din / 4;
  k_f32_to_bf16<<<(n4 + 255) / 256, 256, 0, stream>>>(x, xb, n4);
  n4 = H * Din / 4;
  k_f32_to_bf16<<<(n4 + 255) / 256, 256, 0, stream>>>(W1, W1b, n4);
  n4 = H * H / 4;
  k_f32_to_bf16<<<(n4 + 255) / 256, 256, 0, stream>>>(W2, W2b, n4);
  n4 = Hm * H / 4;
  k_f32_to_bf16<<<(n4 + 255) / 256, 256, 0, stream>>>(Wl1, Wl1b, n4);

  const int MT = (M + BM - 1) / BM;  // 196
  dim3 blk(256);
  const size_t total8 = (size_t)M * H / 8;
  const int apblk = (int)((total8 + 255) / 256);

  // layer 1: h1 = x @ W1^T + b1 (bf16 out, stats fused)
  k_gemm_bt<true, false><<<dim3(H / BN, MT), blk, 0, stream>>>(
      xb, W1b, b1, h1, sum1, sumsq1, M, H, Din);
  k_bn_finalize<<<H / 256, 256, 0, stream>>>(sum1, sumsq1, g1, be1, scale1, shift1, M, H);
  k_bn_apply<<<apblk, 256, 0, stream>>>(h1, scale1, shift1, total8);

  // layer 2: h2 = h1' @ W2^T + b2
  k_gemm_bt<true, false><<<dim3(H / BN, MT), blk, 0, stream>>>(
      h1, W2b, b2, h2, sum2, sumsq2, M, H, H);
  k_bn_finalize<<<H / 256, 256, 0, stream>>>(sum2, sumsq2, g2, be2, scale2, shift2, M, H);
  k_bn_apply<<<apblk, 256, 0, stream>>>(h2, scale2, shift2, total8);

  // layer 3: h3 = relu(h2' @ Wl1^T + bl1), bf16 out (no stats)
  k_gemm_bt<false, true><<<dim3(Hm / BN, MT), blk, 0, stream>>>(
      h2, Wl1b, bl1, h3, nullptr, nullptr, M, Hm, H);

  // head: logits + log_softmax (f32 out)
  k_head<<<(M + 3) / 4, 256, 0, stream>>>(h3, Wl2, bl2, (float*)d_out, M);
}